// Round 1
// baseline (259.505 us; speedup 1.0000x reference)
//
#include <hip/hip_runtime.h>
#include <stdint.h>

#define BS 7
#define HM 50
#define WM 50
#define HH 56
#define WW 56
#define PLANE_IN  (HM * WM)   // 2500
#define PLANE_OUT (HH * WW)   // 3136
#define NPLANES   (64 * 256)  // 16384
#define COUNT_M   51380224.0f // 64*256*56*56 = 49 * 2^20, exact in fp32

// Kernel 1: per-plane 7x7 dilation of the 50x50 seed mask -> 56-row keep
// bitmap (bit w of word h = block_mask[h][w]) + global count of kept pixels.
__global__ __launch_bounds__(256) void dropblock_dilate(
    const float* __restrict__ mask,
    unsigned long long* __restrict__ bitmap,
    unsigned* __restrict__ counter)
{
    __shared__ unsigned long long rowbits[HM];
    __shared__ unsigned long long rowdil[HM];
    __shared__ unsigned cnt;

    const int tid = threadIdx.x;
    const int p = blockIdx.x;

    if (tid < HM) rowbits[tid] = 0ULL;
    if (tid == 0) cnt = 0;
    __syncthreads();

    // Coalesced float4 read of the 2500-float plane; sparse seeds -> LDS atomicOr.
    const float4* mp = reinterpret_cast<const float4*>(mask + (size_t)p * PLANE_IN);
    for (int j = tid; j < PLANE_IN / 4; j += 256) {  // 2500 = 625*4, no tail
        float4 v = mp[j];
        const int e = 4 * j;
        float vv[4] = {v.x, v.y, v.z, v.w};
#pragma unroll
        for (int k = 0; k < 4; ++k) {
            if (vv[k] != 0.0f) {
                int idx = e + k;
                int r = idx / WM;
                int w = idx - r * WM;
                atomicOr(&rowbits[r], 1ULL << w);
            }
        }
    }
    __syncthreads();

    // Row dilation: bit w of s = OR of mask bits [w-6 .. w].
    if (tid < HM) {
        unsigned long long b = rowbits[tid];
        unsigned long long s = b | (b << 1);  // shifts 0..1
        s |= s << 2;                          // shifts 0..3
        s |= s << 3;                          // shifts 0..6
        rowdil[tid] = s;
    }
    __syncthreads();

    // Column dilation + invert + popcount + store bitmap row.
    unsigned pc = 0;
    if (tid < HH) {
        const int h = tid;
        int lo = h - (BS - 1); if (lo < 0) lo = 0;
        int hi = h;            if (hi > HM - 1) hi = HM - 1;
        unsigned long long d = 0ULL;
        for (int r = lo; r <= hi; ++r) d |= rowdil[r];
        unsigned long long keep = ~d & ((1ULL << 56) - 1ULL);
        bitmap[(size_t)p * HH + h] = keep;
        pc = (unsigned)__popcll(keep);
    }
    if (pc) atomicAdd(&cnt, pc);
    __syncthreads();
    if (tid == 0 && cnt) atomicAdd(counter, cnt);
}

// Kernel 2: out = keep ? x * scale : 0. Skips x loads for all-zero nibbles
// (~93% of pixels are dropped, so most x cache lines are never fetched).
__global__ __launch_bounds__(256) void dropblock_scale(
    const float* __restrict__ x,
    const unsigned long long* __restrict__ bitmap,
    const unsigned* __restrict__ counter,
    float* __restrict__ out)
{
    __shared__ unsigned long long bitsLDS[HH];
    __shared__ float s_scale;

    const int tid = threadIdx.x;
    const int p = blockIdx.x;

    if (tid < HH) bitsLDS[tid] = bitmap[(size_t)p * HH + tid];
    if (tid == 0) s_scale = COUNT_M / (float)(*counter);
    __syncthreads();

    const float scale = s_scale;
    const float4* xp = reinterpret_cast<const float4*>(x + (size_t)p * PLANE_OUT);
    float4* op = reinterpret_cast<float4*>(out + (size_t)p * PLANE_OUT);

    for (int j = tid; j < PLANE_OUT / 4; j += 256) {  // 784 float4 per plane
        const int h = j / (WW / 4);        // WW/4 = 14
        const int q = j - h * (WW / 4);
        const int w = 4 * q;
        const unsigned m4 = (unsigned)((bitsLDS[h] >> w) & 0xFULL);
        float4 o = {0.f, 0.f, 0.f, 0.f};
        if (m4) {
            float4 v = xp[j];
            o.x = (m4 & 1u) ? v.x * scale : 0.f;
            o.y = (m4 & 2u) ? v.y * scale : 0.f;
            o.z = (m4 & 4u) ? v.z * scale : 0.f;
            o.w = (m4 & 8u) ? v.w * scale : 0.f;
        }
        op[j] = o;
    }
}

extern "C" void kernel_launch(void* const* d_in, const int* in_sizes, int n_in,
                              void* d_out, int out_size, void* d_ws, size_t ws_size,
                              hipStream_t stream)
{
    const float* x    = (const float*)d_in[0];   // (64,256,56,56) f32
    const float* mask = (const float*)d_in[1];   // (64,256,50,50) f32
    float* out = (float*)d_out;

    unsigned* counter = (unsigned*)d_ws;
    unsigned long long* bitmap =
        (unsigned long long*)((char*)d_ws + 16);  // 16384*56*8 = 7.34 MB

    hipMemsetAsync(counter, 0, sizeof(unsigned), stream);
    dropblock_dilate<<<NPLANES, 256, 0, stream>>>(mask, bitmap, counter);
    dropblock_scale<<<NPLANES, 256, 0, stream>>>(x, bitmap, counter, out);
}

// Round 2
// 109.948 us; speedup vs baseline: 2.3603x; 2.3603x over previous
//
#include <hip/hip_runtime.h>
#include <stdint.h>

#define BS 7
#define HM 50
#define WM 50
#define HH 56
#define WW 56
#define PLANE_IN  (HM * WM)   // 2500
#define PLANE_OUT (HH * WW)   // 3136
#define NPLANES   (64 * 256)  // 16384
#define COUNT_M   51380224.0f // 64*256*56*56 = 49 * 2^20, exact in fp32

// Kernel 1: per-plane 7x7 dilation of the 50x50 seed mask -> 56-row keep
// bitmap (bit w of word h = block_mask[h][w]) + per-plane kept-pixel count
// (plain store; NO global atomics -- same-address atomicAdd across 16384
// blocks serialized at ~12ns each = the 199us stall we measured).
__global__ __launch_bounds__(256) void dropblock_dilate(
    const float* __restrict__ mask,
    unsigned long long* __restrict__ bitmap,
    unsigned* __restrict__ counts)
{
    __shared__ unsigned long long rowbits[HM];
    __shared__ unsigned long long rowdil[HM];
    __shared__ unsigned cnt;

    const int tid = threadIdx.x;
    const int p = blockIdx.x;

    if (tid < HM) rowbits[tid] = 0ULL;
    if (tid == 0) cnt = 0;
    __syncthreads();

    // Coalesced float4 read of the 2500-float plane; sparse seeds -> LDS atomicOr.
    const float4* mp = reinterpret_cast<const float4*>(mask + (size_t)p * PLANE_IN);
    for (int j = tid; j < PLANE_IN / 4; j += 256) {  // 2500 = 625*4, no tail
        float4 v = mp[j];
        const int e = 4 * j;
        float vv[4] = {v.x, v.y, v.z, v.w};
#pragma unroll
        for (int k = 0; k < 4; ++k) {
            if (vv[k] != 0.0f) {
                int idx = e + k;
                int r = idx / WM;
                int w = idx - r * WM;
                atomicOr(&rowbits[r], 1ULL << w);
            }
        }
    }
    __syncthreads();

    // Row dilation: bit w of s = OR of mask bits [w-6 .. w].
    if (tid < HM) {
        unsigned long long b = rowbits[tid];
        unsigned long long s = b | (b << 1);  // shifts 0..1
        s |= s << 2;                          // shifts 0..3
        s |= s << 3;                          // shifts 0..6
        rowdil[tid] = s;
    }
    __syncthreads();

    // Column dilation + invert + popcount + store bitmap row.
    unsigned pc = 0;
    if (tid < HH) {
        const int h = tid;
        int lo = h - (BS - 1); if (lo < 0) lo = 0;
        int hi = h;            if (hi > HM - 1) hi = HM - 1;
        unsigned long long d = 0ULL;
        for (int r = lo; r <= hi; ++r) d |= rowdil[r];
        unsigned long long keep = ~d & ((1ULL << 56) - 1ULL);
        bitmap[(size_t)p * HH + h] = keep;
        pc = (unsigned)__popcll(keep);
    }
    if (pc) atomicAdd(&cnt, pc);  // LDS atomic only (per-block, cheap)
    __syncthreads();
    if (tid == 0) counts[p] = cnt;  // plain store
}

// Kernel 1.5: one block sums the 16384 per-plane counts -> scale factor.
__global__ __launch_bounds__(1024) void dropblock_reduce(
    const unsigned* __restrict__ counts,
    float* __restrict__ scale)
{
    __shared__ unsigned wsum[16];
    unsigned s = 0;
    for (int i = threadIdx.x; i < NPLANES; i += 1024) s += counts[i];
#pragma unroll
    for (int off = 32; off > 0; off >>= 1) s += __shfl_down(s, off, 64);
    const int wave = threadIdx.x >> 6;
    const int lane = threadIdx.x & 63;
    if (lane == 0) wsum[wave] = s;
    __syncthreads();
    if (threadIdx.x == 0) {
        unsigned tot = 0;
#pragma unroll
        for (int w = 0; w < 16; ++w) tot += wsum[w];
        *scale = COUNT_M / (float)tot;
    }
}

// Kernel 2: out = keep ? x * scale : 0. Skips x loads for all-zero nibbles
// (~99% of pixels are dropped, so most x cache lines are never fetched).
__global__ __launch_bounds__(256) void dropblock_scale(
    const float* __restrict__ x,
    const unsigned long long* __restrict__ bitmap,
    const float* __restrict__ scaleptr,
    float* __restrict__ out)
{
    __shared__ unsigned long long bitsLDS[HH];

    const int tid = threadIdx.x;
    const int p = blockIdx.x;

    if (tid < HH) bitsLDS[tid] = bitmap[(size_t)p * HH + tid];
    const float scale = *scaleptr;
    __syncthreads();

    const float4* xp = reinterpret_cast<const float4*>(x + (size_t)p * PLANE_OUT);
    float4* op = reinterpret_cast<float4*>(out + (size_t)p * PLANE_OUT);

    for (int j = tid; j < PLANE_OUT / 4; j += 256) {  // 784 float4 per plane
        const int h = j / (WW / 4);        // WW/4 = 14
        const int q = j - h * (WW / 4);
        const int w = 4 * q;
        const unsigned m4 = (unsigned)((bitsLDS[h] >> w) & 0xFULL);
        float4 o = {0.f, 0.f, 0.f, 0.f};
        if (m4) {
            float4 v = xp[j];
            o.x = (m4 & 1u) ? v.x * scale : 0.f;
            o.y = (m4 & 2u) ? v.y * scale : 0.f;
            o.z = (m4 & 4u) ? v.z * scale : 0.f;
            o.w = (m4 & 8u) ? v.w * scale : 0.f;
        }
        op[j] = o;
    }
}

extern "C" void kernel_launch(void* const* d_in, const int* in_sizes, int n_in,
                              void* d_out, int out_size, void* d_ws, size_t ws_size,
                              hipStream_t stream)
{
    const float* x    = (const float*)d_in[0];   // (64,256,56,56) f32
    const float* mask = (const float*)d_in[1];   // (64,256,50,50) f32
    float* out = (float*)d_out;

    // d_ws layout:
    //   [0, 64KB)           counts[16384] (u32)
    //   [64KB, 64KB+4)      scale (f32)
    //   [65KB(align 1KB)..) bitmap: 16384*56 u64 = 7.34 MB
    unsigned* counts = (unsigned*)d_ws;
    float* scale = (float*)((char*)d_ws + 65536);
    unsigned long long* bitmap = (unsigned long long*)((char*)d_ws + 66560);

    dropblock_dilate<<<NPLANES, 256, 0, stream>>>(mask, bitmap, counts);
    dropblock_reduce<<<1, 1024, 0, stream>>>(counts, scale);
    dropblock_scale<<<NPLANES, 256, 0, stream>>>(x, bitmap, scale, out);
}